// Round 6
// baseline (230.755 us; speedup 1.0000x reference)
//
#include <hip/hip_runtime.h>
#include <math.h>

#define SQ    1024
#define INF   128
#define OUTF  64
#define OHH   256
#define TSTR  66            // floats per table row: 64 dims + denom + pad
#define LOG2E 1.44269504088896f

using bf16x8 = __attribute__((ext_vector_type(8))) __bf16;
using f32x4  = __attribute__((ext_vector_type(4))) float;
using u16x8  = __attribute__((ext_vector_type(8))) unsigned short;

#if __has_builtin(__builtin_amdgcn_exp2f)
#define EXP2F(x) __builtin_amdgcn_exp2f(x)
#else
#define EXP2F(x) __expf((x) * 0.6931471805599453f)
#endif

// ---------------------------------------------------------------------------
// Kernel A: per 64-row tile of flattened (N*S, INF) h:
//   WhM = h @ mean-over-heads(W) via 3-term split bf16 MFMA  -> fp32 rows
//   f' = (h@w_f)*log2e, g' = (h@w_g)*log2e via fp32 dots.
// Batch (bx&31) -> XCD bx%8, matching kR/kTB3/kD consumers.
// ---------------------------------------------------------------------------
__global__ __launch_bounds__(256) void kA(
    const float* __restrict__ h, const float* __restrict__ W,
    const float* __restrict__ a, float* __restrict__ whm,
    float* __restrict__ fo, float* __restrict__ go)
{
    __shared__ __bf16 wmfH[8192];       // B-frag hi (16 KB)
    __shared__ __bf16 wmfL[8192];       // lo residual (16 KB)
    __shared__ float  wfl[INF], wgl[INF]; // prescaled by LOG2E
    __shared__ float  al[2 * OHH];

    const int t    = threadIdx.x;
    const int lane = t & 63;
    const int w    = t >> 6;
    const int bx   = blockIdx.x;
    const int R0   = ((bx & 31) << 10) + ((bx >> 5) << 6);

    al[t]       = a[t];
    al[t + 256] = a[t + 256];

    // WM in B-frag layout, hi/lo split (RNE)
    for (int g = t; g < 2048; g += 256) {
        const int k  = g >> 4;
        const int n0 = (g & 15) << 2;
        const float* Wp = W + k * OHH + n0;
        float4 w0 = *(const float4*)Wp;
        float4 w1 = *(const float4*)(Wp + 64);
        float4 w2 = *(const float4*)(Wp + 128);
        float4 w3 = *(const float4*)(Wp + 192);
        float wm4[4] = {0.25f * (w0.x + w1.x + w2.x + w3.x),
                        0.25f * (w0.y + w1.y + w2.y + w3.y),
                        0.25f * (w0.z + w1.z + w2.z + w3.z),
                        0.25f * (w0.w + w1.w + w2.w + w3.w)};
        const int c = k >> 5, kq = (k >> 3) & 3, id8 = k & 7, T = n0 >> 4;
        const int lbase = kq * 16 + (n0 & 15);
        #pragma unroll
        for (int j = 0; j < 4; ++j) {
            float  v  = wm4[j];
            __bf16 hb = (__bf16)v;
            const int o = ((c * 4 + T) * 64 + lbase + j) * 8 + id8;
            wmfH[o] = hb;
            wmfL[o] = (__bf16)(v - (float)hb);
        }
    }
    __syncthreads();

    // w_f (t<128) / w_g (t>=128)
    {
        const int row = t & 127;
        const float4* Wr = (const float4*)(W + row * OHH);
        const float4* av = (const float4*)(t < 128 ? al : al + OHH);
        float s = 0.f;
        for (int q = 0; q < OHH / 4; ++q) {
            float4 wv = Wr[q], x = av[q];
            s += wv.x * x.x + wv.y * x.y + wv.z * x.z + wv.w * x.w;
        }
        if (t < 128) wfl[row] = s * LOG2E;
        else         wgl[row] = s * LOG2E;
    }
    __syncthreads();

    const int m  = lane & 15;
    const int kq = lane >> 4;
    const float* hrow = h + (size_t)(R0 + w * 16 + m) * INF + kq * 8;

    f32x4 acc[4] = {};
    float sf = 0.f, sg = 0.f;

    #pragma unroll
    for (int c = 0; c < 4; ++c) {
        float4 v0 = *(const float4*)(hrow + c * 32);
        float4 v1 = *(const float4*)(hrow + c * 32 + 4);
        float hv[8] = {v0.x, v0.y, v0.z, v0.w, v1.x, v1.y, v1.z, v1.w};

        float4 wf0 = *(const float4*)(wfl + c * 32 + kq * 8);
        float4 wf1 = *(const float4*)(wfl + c * 32 + kq * 8 + 4);
        float4 wg0 = *(const float4*)(wgl + c * 32 + kq * 8);
        float4 wg1 = *(const float4*)(wgl + c * 32 + kq * 8 + 4);
        float wfv[8] = {wf0.x, wf0.y, wf0.z, wf0.w, wf1.x, wf1.y, wf1.z, wf1.w};
        float wgv[8] = {wg0.x, wg0.y, wg0.z, wg0.w, wg1.x, wg1.y, wg1.z, wg1.w};

        u16x8  ahu;
        bf16x8 alo;
        #pragma unroll
        for (int i = 0; i < 8; ++i) {
            float v = hv[i];
            sf = fmaf(v, wfv[i], sf);
            sg = fmaf(v, wgv[i], sg);
            unsigned u = __float_as_uint(v);
            ahu[i] = (unsigned short)(u >> 16);
            alo[i] = (__bf16)(v - __uint_as_float(u & 0xFFFF0000u));
        }
        bf16x8 ah = __builtin_bit_cast(bf16x8, ahu);

        #pragma unroll
        for (int T = 0; T < 4; ++T) {
            bf16x8 bh = *(const bf16x8*)&wmfH[((c * 4 + T) * 64 + lane) * 8];
            bf16x8 bl = *(const bf16x8*)&wmfL[((c * 4 + T) * 64 + lane) * 8];
            acc[T] = __builtin_amdgcn_mfma_f32_16x16x32_bf16(ah,  bh, acc[T], 0, 0, 0);
            acc[T] = __builtin_amdgcn_mfma_f32_16x16x32_bf16(alo, bh, acc[T], 0, 0, 0);
            acc[T] = __builtin_amdgcn_mfma_f32_16x16x32_bf16(ah,  bl, acc[T], 0, 0, 0);
        }
    }

    sf += __shfl_xor(sf, 16, 64); sf += __shfl_xor(sf, 32, 64);
    sg += __shfl_xor(sg, 16, 64); sg += __shfl_xor(sg, 32, 64);
    if (lane < 16) {
        fo[R0 + w * 16 + m] = sf;
        go[R0 + w * 16 + m] = sg;
    }

    #pragma unroll
    for (int T = 0; T < 4; ++T) {
        #pragma unroll
        for (int r = 0; r < 4; ++r) {
            whm[(size_t)(R0 + w * 16 + kq * 4 + r) * OUTF + T * 16 + m] = acc[T][r];
        }
    }
}

// ---------------------------------------------------------------------------
// Kernel R: brute-force exact ranking.
//   Key K_e = sortable(g'_e)<<32 | e  (unique -> exact permutation).
//   rank_e = #{k : K_k < K_e}. 512 blocks (16/batch); 4 threads/element scan
//   rotated quarters of the batch's 1024 keys from LDS, combine via 2
//   shfl_xor, scatter gs[rank], pi[rank].
// ---------------------------------------------------------------------------
__global__ __launch_bounds__(256) void kR(
    const float* __restrict__ gi, float* __restrict__ gs_out,
    unsigned short* __restrict__ piG)
{
    __shared__ unsigned long long keys[1024];   // 8 KB

    const int t  = threadIdx.x;
    const int n  = blockIdx.x & 31;
    const int qb = blockIdx.x >> 5;             // 0..15: element block

    for (int i = t; i < 1024; i += 256) {
        unsigned u   = __float_as_uint(gi[n * SQ + i]);
        unsigned key = (u & 0x80000000u) ? ~u : (u | 0x80000000u);
        keys[i] = ((unsigned long long)key << 32) | (unsigned)i;
    }
    __syncthreads();

    const int el = t >> 2;          // 0..63: element within block
    const int qt = t & 3;           // scan quarter
    const int e  = qb * 64 + el;    // original index
    const unsigned long long Ke = keys[e];

    int cnt = 0;
    #pragma unroll 16
    for (int s = 0; s < 256; ++s) {
        int idx = qt * 256 + ((s + qt * 4) & 255);
        cnt += (keys[idx] < Ke) ? 1 : 0;
    }
    cnt += __shfl_xor(cnt, 1, 64);
    cnt += __shfl_xor(cnt, 2, 64);

    if (qt == 0) {
        unsigned kk = (unsigned)(Ke >> 32);
        unsigned uu = (kk & 0x80000000u) ? (kk & 0x7fffffffu) : ~kk;
        gs_out[n * SQ + cnt] = __uint_as_float(uu);
        piG[n * SQ + cnt]    = (unsigned short)e;
    }
}

// ---------------------------------------------------------------------------
// Kernel TB3: fused sub-chunk-totals + scan + table emit, 2 blocks/CU.
//   Pre[r][d] = sum_{t<r}  2^{0.1 g'_(t)} WhM[pi(t)][d]   (r in [0,1024])
//   Suf[r][d] = sum_{t>=r} 2^{g'_(t)}     WhM[pi(t)][d]
// 512 blocks: bx = k*32 + n, k in [0,16): dir = k&1, grp = k>>1 in [0,8).
// Totals at 32-row sub-chunk granularity: wave wid computes sub-chunks
// sc = s8*4+wid (s8 = 0..7) into LDS. The s8 == grp iteration IS the wave's
// emit sub-chunk: its 32 gathered values/weights are kept in registers
// across the barrier, so the emit phase re-gathers NOTHING.
// ---------------------------------------------------------------------------
__global__ __launch_bounds__(256) void kTB3(
    const float* __restrict__ whm, const unsigned short* __restrict__ piG,
    const float* __restrict__ gs,
    float* __restrict__ sufA, float* __restrict__ preB)
{
    __shared__ float          wsel[1024];    // 4 KB: this dir's weights
    __shared__ unsigned short piL[1024];     // 2 KB
    __shared__ float          tot[32][TSTR]; // 8.4 KB: 32-row sub-chunk totals

    const int t    = threadIdx.x;
    const int lane = t & 63;
    const int wid  = t >> 6;
    const int n    = blockIdx.x & 31;
    const int k    = blockIdx.x >> 5;   // 0..15
    const int dir  = k & 1;
    const int grp  = k >> 1;            // 0..7

    for (int i = t; i < 1024; i += 256) {
        float g = gs[n * SQ + i];
        wsel[i] = EXP2F(dir ? g : 0.1f * g);
        piL[i]  = piG[n * SQ + i];
    }
    __syncthreads();

    const float* wb = whm + (size_t)n * (SQ * OUTF);

    // ---- totals: wave wid covers sub-chunks s8*4+wid; own emit sub-chunk
    //      (s8 == grp) cached in registers (static indexing only)
    float keepV[32], keepW[32];
    for (int s8 = 0; s8 < 8; ++s8) {
        const int sc = s8 * 4 + wid;
        float acc = 0.f, dacc = 0.f;
        #pragma unroll
        for (int h16 = 0; h16 < 2; ++h16) {
            float vals[16], wvv[16];
            #pragma unroll
            for (int u = 0; u < 16; ++u) {
                int tt = sc * 32 + h16 * 16 + u;
                wvv[u]  = wsel[tt];
                vals[u] = wb[(size_t)piL[tt] * OUTF + lane];
            }
            #pragma unroll
            for (int u = 0; u < 16; ++u) {
                acc  = fmaf(wvv[u], vals[u], acc);
                dacc += wvv[u];
            }
            if (s8 == grp) {
                #pragma unroll
                for (int u = 0; u < 16; ++u) {
                    keepV[h16 * 16 + u] = vals[u];
                    keepW[h16 * 16 + u] = wvv[u];
                }
            }
        }
        tot[sc][lane] = acc;
        if (lane == 0) tot[sc][64] = dacc;
    }
    __syncthreads();

    // ---- emit sub-chunk sc = grp*4 + wid from registers
    const int sc = grp * 4 + wid;
    float base = 0.f, based = 0.f;
    if (dir == 0) {
        for (int s = 0; s < sc; ++s) {
            base  += tot[s][lane];
            based += tot[s][64];
        }
        float* Gp = preB + ((size_t)n * 1025 + (size_t)sc * 32) * TSTR;
        float acc = base, dacc = based;
        #pragma unroll
        for (int u = 0; u < 32; ++u) {
            float* row = Gp + (size_t)u * TSTR;
            row[lane] = acc;                 // prefix: store BEFORE add
            if (lane == 0) row[64] = dacc;
            acc  = fmaf(keepW[u], keepV[u], acc);
            dacc += keepW[u];
        }
        if (sc == 31) {                      // boundary row r = 1024
            float* row = preB + ((size_t)n * 1025 + 1024) * TSTR;
            row[lane] = acc;
            if (lane == 0) row[64] = dacc;
        }
    } else {
        for (int s = sc + 1; s < 32; ++s) {
            base  += tot[s][lane];
            based += tot[s][64];
        }
        float* Gs = sufA + ((size_t)n * 1025 + (size_t)sc * 32) * TSTR;
        float acc = base, dacc = based;
        #pragma unroll
        for (int u = 31; u >= 0; --u) {
            acc  = fmaf(keepW[u], keepV[u], acc);   // suffix: add THEN store
            dacc += keepW[u];
            float* row = Gs + (size_t)u * TSTR;
            row[lane] = acc;
            if (lane == 0) row[64] = dacc;
        }
        if (sc == 31) {                      // boundary row r = 1024
            float* row = sufA + ((size_t)n * 1025 + 1024) * TSTR;
            row[lane] = 0.f;
            if (lane == 0) row[64] = 0.f;
        }
    }
}

// ---------------------------------------------------------------------------
// Kernel D: per (batch, 64-row i-tile): binary-search r_i over sorted g',
// combine one Suf row + one Pre row, normalize, ELU, store. Fully unrolled
// so all 32 table-row loads issue early and pipeline.
// ---------------------------------------------------------------------------
__global__ __launch_bounds__(256) void kD(
    const float* __restrict__ fi, const float* __restrict__ gs,
    const float* __restrict__ sufA, const float* __restrict__ preB,
    float* __restrict__ out)
{
    __shared__ float gsL[1025];

    const int t    = threadIdx.x;
    const int lane = t & 63;
    const int wid  = t >> 6;
    const int n    = blockIdx.x & 31;       // XCD-pinned w/ producer
    const int i0   = (blockIdx.x >> 5) * 64;

    for (int q = t; q < 1024; q += 256) gsL[q] = gs[n * SQ + q];
    if (t == 0) gsL[1024] = 3.0e38f;
    __syncthreads();

    const float myf = fi[n * SQ + i0 + wid * 16 + (lane & 15)];
    const float v = -myf;
    int lo = 0, hi = 1024;
    #pragma unroll
    for (int it = 0; it < 10; ++it) {
        int mid = (lo + hi) >> 1;
        bool gt = gsL[mid] > v;
        hi = gt ? mid : hi;
        lo = gt ? lo : mid + 1;
    }

    const float* SA = sufA + (size_t)n * 1025 * TSTR;
    const float* PB = preB + (size_t)n * 1025 * TSTR;
    const size_t orow0 = (size_t)(n * SQ + i0 + wid * 16);

    #pragma unroll
    for (int s = 0; s < 16; ++s) {
        int   r  = __shfl(lo,  s, 64);
        float fv = __shfl(myf, s, 64);
        const float* sa = SA + (size_t)r * TSTR;
        const float* pb = PB + (size_t)r * TSTR;
        float sv = sa[lane], pv = pb[lane];
        float sd = sa[64],  pd = pb[64];
        float eP = EXP2F(fv);
        float eN = EXP2F(0.1f * fv);
        float num = eP * sv + eN * pv;
        float den = eP * sd + eN * pd;
        float o = num / den;
        o = o > 0.f ? o : expm1f(o);
        out[(orow0 + s) * OUTF + lane] = o;
    }
}

extern "C" void kernel_launch(void* const* d_in, const int* in_sizes, int n_in,
                              void* d_out, int out_size, void* d_ws, size_t ws_size,
                              hipStream_t stream) {
    const float* h = (const float*)d_in[0];
    // d_in[1] = adj : unused by the reference computation
    const float* W = (const float*)d_in[2];
    const float* a = (const float*)d_in[3];

    char* ws = (char*)d_ws;
    const size_t MB = 1024 * 1024;
    const size_t KB = 1024;
    float*          whm  = (float*)(ws);                        // 8 MB
    float*          fb   = (float*)(ws + 8 * MB);               // 128 KB
    float*          gb   = (float*)(ws + 8 * MB + 128 * KB);    // 128 KB
    float*          gsO  = (float*)(ws + 8 * MB + 256 * KB);    // 128 KB
    unsigned short* piG  = (unsigned short*)(ws + 8 * MB + 384 * KB); // 64 KB
    float*          sufA = (float*)(ws + 10 * MB);              // 8.26 MB
    float*          preB = (float*)(ws + 19 * MB);              // 8.26 MB
    float*          outp = (float*)d_out;

    hipLaunchKernelGGL(kA,   dim3(512), dim3(256), 0, stream, h, W, a, whm, fb, gb);
    hipLaunchKernelGGL(kR,   dim3(512), dim3(256), 0, stream, gb, gsO, piG);
    hipLaunchKernelGGL(kTB3, dim3(512), dim3(256), 0, stream, whm, piG, gsO, sufA, preB);
    hipLaunchKernelGGL(kD,   dim3(512), dim3(256), 0, stream, fb, gsO, sufA, preB, outp);
}